// Round 6
// baseline (124.516 us; speedup 1.0000x reference)
//
#include <hip/hip_runtime.h>

constexpr int kB = 4, kC = 64, kH = 64, kW = 64, kN = kH * kW;
constexpr float kEps = 1e-5f;
constexpr int SPLIT = 8;

typedef __attribute__((ext_vector_type(8))) short short8;
typedef __attribute__((ext_vector_type(4))) float f32x4;
typedef unsigned short u16;

__device__ inline unsigned pkbf(float a, float b) {  // RNE pack
  unsigned ua = __float_as_uint(a), ub = __float_as_uint(b);
  ua += 0x7fff + ((ua >> 16) & 1);
  ub += 0x7fff + ((ub >> 16) & 1);
  return (ua >> 16) | (ub & 0xffff0000u);
}

__device__ inline float fexp2(float x) { return __builtin_amdgcn_exp2f(x); }

// ---- w[oc][ic][3][3] fp32 -> wA bf16 [oc][khw*64 + ic]
__global__ __launch_bounds__(256) void prep_w_kernel(const float* __restrict__ w,
                                                     u16* __restrict__ wA) {
  int idx = blockIdx.x * 256 + threadIdx.x;
  if (idx < 64 * 576) {
    int oc = idx / 576, r = idx - oc * 576;
    int khw = r >> 6, ic = r & 63;
    float v = w[(oc * 64 + ic) * 9 + khw];
    unsigned u = __float_as_uint(v);
    u += 0x7fff + ((u >> 16) & 1);
    wA[idx] = (u16)(u >> 16);
  }
}

// ---- conv 3x3 SAME + bias (bf16 MFMA) + fused per-channel stats partials.
__global__ __launch_bounds__(256) void conv_kernel(const float* __restrict__ x,
                                                   const u16* __restrict__ wA,
                                                   const float* __restrict__ bias,
                                                   float* __restrict__ y,
                                                   float* __restrict__ sums) {
  const int tid = threadIdx.x;
  const int lane = tid & 63;
  const int wv = tid >> 6;
  const int bx = blockIdx.x;
  const int b = bx >> 7;
  const int h = (bx & 127) >> 1;
  const int w0 = (bx & 1) * 32;
  const int lw = lane & 15, lg = lane >> 4;

  __shared__ __align__(16) u16 xt[3 * 40 * 64];

#pragma unroll
  for (int rep = 0; rep < 4; ++rep) {
    int idx = rep * 256 + tid;
    if (idx < 960) {
      int kh = idx / 320;
      int t = idx - kh * 320;
      int gw = t >> 5, icp = t & 31;
      int wb = w0 - 4 + gw * 4;
      int hh = h + kh - 1;
      float4 va = {0.f, 0.f, 0.f, 0.f}, vb = {0.f, 0.f, 0.f, 0.f};
      if (hh >= 0 && hh < 64 && wb >= 0 && wb < 64) {
        va = *(const float4*)&x[((b * 64 + icp * 2) * 64 + hh) * 64 + wb];
        vb = *(const float4*)&x[((b * 64 + icp * 2 + 1) * 64 + hh) * 64 + wb];
      }
      float av[4] = {va.x, va.y, va.z, va.w};
      float bv[4] = {vb.x, vb.y, vb.z, vb.w};
#pragma unroll
      for (int j = 0; j < 4; ++j) {
        int wc = gw * 4 + j;
        *(unsigned*)&xt[(kh * 40 + wc) * 64 + (((icp >> 2) ^ (wc & 7)) * 8 + (icp & 3) * 2)] =
            pkbf(av[j], bv[j]);
      }
    }
  }
  __syncthreads();

  const int oc0 = wv * 16;
  short8 af[18];
#pragma unroll
  for (int kc = 0; kc < 18; ++kc)
    af[kc] = *(const short8*)&wA[(oc0 + lw) * 576 + kc * 32 + lg * 8];

  f32x4 acc[2];
  acc[0] = (f32x4){0.f, 0.f, 0.f, 0.f};
  acc[1] = (f32x4){0.f, 0.f, 0.f, 0.f};
#pragma unroll
  for (int kc = 0; kc < 18; ++kc) {
    const int khw = kc >> 1;
    const int kh = khw / 3, kwv = khw % 3;
#pragma unroll
    for (int nt = 0; nt < 2; ++nt) {
      int wc = nt * 16 + lw + kwv + 3;
      short8 bf = *(const short8*)&xt[(kh * 40 + wc) * 64 + ((((kc & 1) * 4 + lg) ^ (wc & 7)) * 8)];
      acc[nt] = __builtin_amdgcn_mfma_f32_16x16x32_bf16(af[kc], bf, acc[nt], 0, 0, 0);
    }
  }
  float yv[2][4];
#pragma unroll
  for (int r = 0; r < 4; ++r) {
    float bv = bias[oc0 + lg * 4 + r];
    yv[0][r] = acc[0][r] + bv;
    yv[1][r] = acc[1][r] + bv;
  }
#pragma unroll
  for (int nt = 0; nt < 2; ++nt)
#pragma unroll
    for (int r = 0; r < 4; ++r)
      y[((b * 64 + oc0 + lg * 4 + r) * 64 + h) * 64 + w0 + nt * 16 + lw] = yv[nt][r];
  // stats partials: sum over this block's 64 w positions per oc
  float sv[4], qv[4];
#pragma unroll
  for (int r = 0; r < 4; ++r) {
    sv[r] = yv[0][r] + yv[1][r];
    qv[r] = yv[0][r] * yv[0][r] + yv[1][r] * yv[1][r];
  }
#pragma unroll
  for (int m = 1; m < 16; m <<= 1)
#pragma unroll
    for (int r = 0; r < 4; ++r) {
      sv[r] += __shfl_xor(sv[r], m);
      qv[r] += __shfl_xor(qv[r], m);
    }
  if (lw == 0) {
    const int bin = bx & 7;
#pragma unroll
    for (int r = 0; r < 4; ++r) {
      int oc = oc0 + lg * 4 + r;
      atomicAdd(&sums[bin * 128 + oc], sv[r]);
      atomicAdd(&sums[bin * 128 + 64 + oc], qv[r]);
    }
  }
}

// ---- BN + PReLU (AB finalized inline from sums) -> feat f32; fbfA/fbfQ/fbfB bf16 frags
__global__ __launch_bounds__(256) void pack_kernel(const float* __restrict__ y,
                                                   const float* __restrict__ sums,
                                                   const float* __restrict__ scale,
                                                   const float* __restrict__ bias,
                                                   const float* __restrict__ pa,
                                                   float* __restrict__ feat,
                                                   u16* __restrict__ fbfA,
                                                   u16* __restrict__ fbfQ,
                                                   u16* __restrict__ fbfB) {
  __shared__ float ls[64 * 65];
  __shared__ float ABl[128];
  const int tid = threadIdx.x;
  const int b = blockIdx.x >> 6;
  const int n0 = (blockIdx.x & 63) << 6;
  if (tid < 64) {
    float s = 0.f, q = 0.f;
#pragma unroll
    for (int bin = 0; bin < 8; ++bin) {
      s += sums[bin * 128 + tid];
      q += sums[bin * 128 + 64 + tid];
    }
    float mean = s * (1.f / 16384.f);
    float var = q * (1.f / 16384.f) - mean * mean;
    float A = scale[tid] * rsqrtf(var + kEps);
    ABl[tid] = A;
    ABl[64 + tid] = bias[tid] - mean * A;
  }
  __syncthreads();
  {
    const int c = tid >> 2, nj = (tid & 3) << 4;
    const float A = ABl[c], Bc = ABl[64 + c], a = pa[0];
    const float* yp = y + ((b * kC + c) * kN) + n0 + nj;
    float f[16];
#pragma unroll
    for (int v = 0; v < 4; ++v) {
      float4 xv = *(const float4*)(yp + v * 4);
      float t;
      t = fmaf(A, xv.x, Bc); f[v * 4 + 0] = t >= 0.f ? t : a * t;
      t = fmaf(A, xv.y, Bc); f[v * 4 + 1] = t >= 0.f ? t : a * t;
      t = fmaf(A, xv.z, Bc); f[v * 4 + 2] = t >= 0.f ? t : a * t;
      t = fmaf(A, xv.w, Bc); f[v * 4 + 3] = t >= 0.f ? t : a * t;
    }
    float* fo = feat + ((b * kC + c) * kN) + n0 + nj;
#pragma unroll
    for (int v = 0; v < 4; ++v) {
      float4 fv = {f[v * 4 + 0], f[v * 4 + 1], f[v * 4 + 2], f[v * 4 + 3]};
      *(float4*)(fo + v * 4) = fv;
    }
#pragma unroll
    for (int v = 0; v < 16; ++v) ls[c * 65 + nj + v] = f[v];
  }
  __syncthreads();
  {  // fbfA + fbfQ: chunk = (pt 0..3, kc 0..1)
    int chunk = tid >> 5, pt = chunk >> 1, kc = chunk & 1;
    int lp2 = (tid & 31) * 2;
    size_t cidx = ((size_t)((b * 256 + (n0 >> 4) + pt) * 2 + kc)) * 512;
    u16* dstA = fbfA + cidx;
    u16* dstQ = fbfQ + cidx;
    const float cl = -1.4426950408889634f;
#pragma unroll
    for (int e = 0; e < 2; ++e) {
      int L = lp2 + e;
      int n = pt * 16 + (L & 15);
      int cb = kc * 32 + (L >> 4) * 8;
      float v[8];
#pragma unroll
      for (int r = 0; r < 8; ++r) v[r] = ls[(cb + r) * 65 + n];
      uint4 o = {pkbf(v[0], v[1]), pkbf(v[2], v[3]), pkbf(v[4], v[5]), pkbf(v[6], v[7])};
      *(uint4*)&dstA[L * 8] = o;
      uint4 oq = {pkbf(v[0] * cl, v[1] * cl), pkbf(v[2] * cl, v[3] * cl),
                  pkbf(v[4] * cl, v[5] * cl), pkbf(v[6] * cl, v[7] * cl)};
      *(uint4*)&dstQ[L * 8] = oq;
    }
  }
  {  // fbfB: chunk = (jt 0..1, ct 0..3)
    int chunk = tid >> 5, jt = chunk >> 2, ct = chunk & 3;
    int lp2 = (tid & 31) * 2;
    u16* dst = fbfB + ((size_t)((b * 128 + (n0 >> 5) + jt) * 4 + ct)) * 512;
#pragma unroll
    for (int e = 0; e < 2; ++e) {
      int L = lp2 + e;
      int c = ct * 16 + (L & 15);
      int nb = jt * 32 + (L >> 4) * 8;
      float v[8];
#pragma unroll
      for (int r = 0; r < 8; ++r) v[r] = ls[c * 65 + nb + r];
      uint4 o = {pkbf(v[0], v[1]), pkbf(v[2], v[3]), pkbf(v[4], v[5]), pkbf(v[6], v[7])};
      *(uint4*)&dst[L * 8] = o;
    }
  }
}

// ---- barrier-free pipelined MFMA flash attention. grid=(b,itb,s), SPLIT=8.
// Per iter: PV(jt-1) first (covers exp/LDS chain), then S(jt)->exp2->P write.
__global__ __launch_bounds__(256, 2) void attn_kernel(const u16* __restrict__ fbfA,
                                                      const u16* __restrict__ fbfQ,
                                                      const u16* __restrict__ fbfB,
                                                      float* __restrict__ Op,
                                                      float* __restrict__ lp) {
  const int tid = threadIdx.x;
  const int lane = tid & 63;
  const int w = tid >> 6;
  const int bx = blockIdx.x;
  const int s = bx & 7, itb = (bx >> 3) & 15, b = bx >> 7;
  const int c15 = lane & 15, g = lane >> 4;

  __shared__ __align__(16) u16 Ps[4][64 * 40];
  u16* ps = &Ps[w][0];
  const int pw_off = c15 * 40 + g * 4;
  const int pr_off = c15 * 40 + g * 8;

  const uint4* fAb = (const uint4*)fbfA + (size_t)b * 32768 + lane;
  const uint4* fQb = (const uint4*)fbfQ + (size_t)b * 32768 + lane;
  const uint4* fBb = (const uint4*)fbfB + (size_t)b * 32768 + lane;

  // Q frags (pre-scaled by -log2e in fbfQ)
  uint4 qf[4][2];
  const int ptq = itb * 16 + w * 4;
#pragma unroll
  for (int it = 0; it < 4; ++it)
#pragma unroll
    for (int kc = 0; kc < 2; ++kc)
      qf[it][kc] = fQb[(size_t)((ptq + it) * 2 + kc) * 64];

  const short8 ones = {0x3F80, 0x3F80, 0x3F80, 0x3F80, 0x3F80, 0x3F80, 0x3F80, 0x3F80};

  f32x4 oacc[4][4];
  f32x4 lacc[4];
#pragma unroll
  for (int it = 0; it < 4; ++it) {
    lacc[it] = (f32x4){0.f, 0.f, 0.f, 0.f};
#pragma unroll
    for (int ct = 0; ct < 4; ++ct) oacc[it][ct] = (f32x4){0.f, 0.f, 0.f, 0.f};
  }

  const uint4* pA = fAb + (size_t)(s * 64) * 64;
  const uint4* pV = fBb + (size_t)(s * 64) * 64;

  uint4 vp0, vp1, vp2, vp3;
  {  // prologue jt=0: S -> exp2 -> P write; latch V
    uint4 a00 = pA[0], a01 = pA[64], a10 = pA[128], a11 = pA[192];
    vp0 = pV[0]; vp1 = pV[64]; vp2 = pV[128]; vp3 = pV[192];
    pA += 256; pV += 256;
    f32x4 sv[2][4];
#pragma unroll
    for (int it = 0; it < 4; ++it) {
      f32x4 z0 = (f32x4){0.f, 0.f, 0.f, 0.f};
      z0 = __builtin_amdgcn_mfma_f32_16x16x32_bf16(*(short8*)&a00, *(short8*)&qf[it][0], z0, 0, 0, 0);
      z0 = __builtin_amdgcn_mfma_f32_16x16x32_bf16(*(short8*)&a01, *(short8*)&qf[it][1], z0, 0, 0, 0);
      sv[0][it] = z0;
      f32x4 z1 = (f32x4){0.f, 0.f, 0.f, 0.f};
      z1 = __builtin_amdgcn_mfma_f32_16x16x32_bf16(*(short8*)&a10, *(short8*)&qf[it][0], z1, 0, 0, 0);
      z1 = __builtin_amdgcn_mfma_f32_16x16x32_bf16(*(short8*)&a11, *(short8*)&qf[it][1], z1, 0, 0, 0);
      sv[1][it] = z1;
    }
#pragma unroll
    for (int it = 0; it < 4; ++it)
#pragma unroll
      for (int jt2 = 0; jt2 < 2; ++jt2) {
        float p0 = fexp2(sv[jt2][it][0]);
        float p1 = fexp2(sv[jt2][it][1]);
        float p2 = fexp2(sv[jt2][it][2]);
        float p3 = fexp2(sv[jt2][it][3]);
        uint2 d;
        d.x = __builtin_amdgcn_perm(__float_as_uint(p1), __float_as_uint(p0), 0x07060302u);
        d.y = __builtin_amdgcn_perm(__float_as_uint(p3), __float_as_uint(p2), 0x07060302u);
        *(uint2*)&ps[pw_off + it * 640 + jt2 * 16] = d;
      }
  }

#pragma unroll 2
  for (int jt = 1; jt < 16; ++jt) {
    // P(jt-1) from LDS; V(jt) loads issued early
    short8 pf[4];
#pragma unroll
    for (int it = 0; it < 4; ++it) pf[it] = *(const short8*)&ps[pr_off + it * 640];
    uint4 a00 = pA[0], a01 = pA[64], a10 = pA[128], a11 = pA[192];
    uint4 vc0 = pV[0], vc1 = pV[64], vc2 = pV[128], vc3 = pV[192];
    pA += 256; pV += 256;
    // PV(jt-1)
#pragma unroll
    for (int it = 0; it < 4; ++it) {
      lacc[it] = __builtin_amdgcn_mfma_f32_16x16x32_bf16(pf[it], ones, lacc[it], 0, 0, 0);
      oacc[it][0] = __builtin_amdgcn_mfma_f32_16x16x32_bf16(pf[it], *(short8*)&vp0, oacc[it][0], 0, 0, 0);
      oacc[it][1] = __builtin_amdgcn_mfma_f32_16x16x32_bf16(pf[it], *(short8*)&vp1, oacc[it][1], 0, 0, 0);
      oacc[it][2] = __builtin_amdgcn_mfma_f32_16x16x32_bf16(pf[it], *(short8*)&vp2, oacc[it][2], 0, 0, 0);
      oacc[it][3] = __builtin_amdgcn_mfma_f32_16x16x32_bf16(pf[it], *(short8*)&vp3, oacc[it][3], 0, 0, 0);
    }
    // S(jt)
    f32x4 sv[2][4];
#pragma unroll
    for (int it = 0; it < 4; ++it) {
      f32x4 z0 = (f32x4){0.f, 0.f, 0.f, 0.f};
      z0 = __builtin_amdgcn_mfma_f32_16x16x32_bf16(*(short8*)&a00, *(short8*)&qf[it][0], z0, 0, 0, 0);
      z0 = __builtin_amdgcn_mfma_f32_16x16x32_bf16(*(short8*)&a01, *(short8*)&qf[it][1], z0, 0, 0, 0);
      sv[0][it] = z0;
      f32x4 z1 = (f32x4){0.f, 0.f, 0.f, 0.f};
      z1 = __builtin_amdgcn_mfma_f32_16x16x32_bf16(*(short8*)&a10, *(short8*)&qf[it][0], z1, 0, 0, 0);
      z1 = __builtin_amdgcn_mfma_f32_16x16x32_bf16(*(short8*)&a11, *(short8*)&qf[it][1], z1, 0, 0, 0);
      sv[1][it] = z1;
    }
    // exp2 -> P(jt)
#pragma unroll
    for (int it = 0; it < 4; ++it)
#pragma unroll
      for (int jt2 = 0; jt2 < 2; ++jt2) {
        float p0 = fexp2(sv[jt2][it][0]);
        float p1 = fexp2(sv[jt2][it][1]);
        float p2 = fexp2(sv[jt2][it][2]);
        float p3 = fexp2(sv[jt2][it][3]);
        uint2 d;
        d.x = __builtin_amdgcn_perm(__float_as_uint(p1), __float_as_uint(p0), 0x07060302u);
        d.y = __builtin_amdgcn_perm(__float_as_uint(p3), __float_as_uint(p2), 0x07060302u);
        *(uint2*)&ps[pw_off + it * 640 + jt2 * 16] = d;
      }
    vp0 = vc0; vp1 = vc1; vp2 = vc2; vp3 = vc3;
  }
  {  // epilogue PV(15)
    short8 pf[4];
#pragma unroll
    for (int it = 0; it < 4; ++it) pf[it] = *(const short8*)&ps[pr_off + it * 640];
#pragma unroll
    for (int it = 0; it < 4; ++it) {
      lacc[it] = __builtin_amdgcn_mfma_f32_16x16x32_bf16(pf[it], ones, lacc[it], 0, 0, 0);
      oacc[it][0] = __builtin_amdgcn_mfma_f32_16x16x32_bf16(pf[it], *(short8*)&vp0, oacc[it][0], 0, 0, 0);
      oacc[it][1] = __builtin_amdgcn_mfma_f32_16x16x32_bf16(pf[it], *(short8*)&vp1, oacc[it][1], 0, 0, 0);
      oacc[it][2] = __builtin_amdgcn_mfma_f32_16x16x32_bf16(pf[it], *(short8*)&vp2, oacc[it][2], 0, 0, 0);
      oacc[it][3] = __builtin_amdgcn_mfma_f32_16x16x32_bf16(pf[it], *(short8*)&vp3, oacc[it][3], 0, 0, 0);
    }
  }

  float* Ow = Op + (size_t)(bx * 4 + w) * 4096;
#pragma unroll
  for (int it = 0; it < 4; ++it)
#pragma unroll
    for (int ct = 0; ct < 4; ++ct)
#pragma unroll
      for (int r = 0; r < 4; ++r)
        Ow[(it * 16 + g * 4 + r) * 64 + ct * 16 + c15] = oacc[it][ct][r];
  if (c15 == 0) {
    float* lw_ = lp + (size_t)(bx * 4 + w) * 64;
#pragma unroll
    for (int it = 0; it < 4; ++it)
#pragma unroll
      for (int r = 0; r < 4; ++r) lw_[it * 16 + g * 4 + r] = lacc[it][r];
  }
}

// ---- combine: out[c][n] = gamma * (sum_s Op)/(sum_s lp) + feat
__global__ __launch_bounds__(256) void combine_kernel(const float* __restrict__ Op,
                                                      const float* __restrict__ lp,
                                                      const float* __restrict__ feat,
                                                      const float* __restrict__ gamma_p,
                                                      float* __restrict__ out) {
  const int tid = threadIdx.x;
  const int bx = blockIdx.x;  // b*64 + it64
  const int b = bx >> 6, it64 = bx & 63;
  const int itb = it64 >> 2, w = it64 & 3;
  __shared__ float tr[64 * 65];
  __shared__ float linv[64];
  if (tid < 64) {
    float sum = 0.f;
#pragma unroll
    for (int s = 0; s < SPLIT; ++s)
      sum += lp[(size_t)(((b * 16 + itb) * 8 + s) * 4 + w) * 64 + tid];
    linv[tid] = 1.f / sum;
  }
  __syncthreads();
  const float gm = gamma_p[0];
#pragma unroll
  for (int rr = 0; rr < 4; ++rr) {
    int flat4 = rr * 256 + tid;
    int i = flat4 >> 4, c4 = (flat4 & 15) * 4;
    float4 acc = {0.f, 0.f, 0.f, 0.f};
#pragma unroll
    for (int s = 0; s < SPLIT; ++s) {
      float4 v = *(const float4*)&Op[(size_t)(((b * 16 + itb) * 8 + s) * 4 + w) * 4096 + i * 64 + c4];
      acc.x += v.x; acc.y += v.y; acc.z += v.z; acc.w += v.w;
    }
    float sc = gm * linv[i];
    tr[(c4 + 0) * 65 + i] = acc.x * sc;
    tr[(c4 + 1) * 65 + i] = acc.y * sc;
    tr[(c4 + 2) * 65 + i] = acc.z * sc;
    tr[(c4 + 3) * 65 + i] = acc.w * sc;
  }
  __syncthreads();
#pragma unroll
  for (int rr = 0; rr < 4; ++rr) {
    int flat4 = rr * 256 + tid;
    int c = flat4 >> 4, i4 = (flat4 & 15) * 4;
    float4 fv = *(const float4*)&feat[(size_t)(b * 64 + c) * 4096 + it64 * 64 + i4];
    float4 ov;
    ov.x = tr[c * 65 + i4 + 0] + fv.x;
    ov.y = tr[c * 65 + i4 + 1] + fv.y;
    ov.z = tr[c * 65 + i4 + 2] + fv.z;
    ov.w = tr[c * 65 + i4 + 3] + fv.w;
    *(float4*)&out[(size_t)(b * 64 + c) * 4096 + it64 * 64 + i4] = ov;
  }
}

extern "C" void kernel_launch(void* const* d_in, const int* in_sizes, int n_in,
                              void* d_out, int out_size, void* d_ws, size_t ws_size,
                              hipStream_t stream) {
  (void)in_sizes; (void)n_in; (void)out_size; (void)ws_size;
  const float* x        = (const float*)d_in[0];
  const float* conv_w   = (const float*)d_in[1];
  const float* conv_b   = (const float*)d_in[2];
  const float* bn_scale = (const float*)d_in[3];
  const float* bn_bias  = (const float*)d_in[4];
  const float* prelu_a  = (const float*)d_in[5];
  const float* gamma    = (const float*)d_in[6];
  float* out = (float*)d_out;

  float* feat = (float*)d_ws;                          // 1,048,576 f32
  u16* fbfA = (u16*)(feat + kB * kC * kN);             // 1,048,576 u16
  u16* fbfQ = fbfA + kB * kC * kN;                     // 1,048,576 u16
  u16* fbfB = fbfQ + kB * kC * kN;                     // 1,048,576 u16
  u16* wA = fbfB + kB * kC * kN;                       // 36,864 u16
  float* sums = (float*)(wA + 36864);                  // 1024 f32 (8 bins x 128)
  float* Op = sums + 1024;                             // 2048*4096 f32 (33.5 MB)
  float* lp = Op + (size_t)2048 * 4096;                // 131,072 f32

  float* y = out;  // conv scratch in d_out; overwritten by combine at the end

  (void)hipMemsetAsync(sums, 0, 1024 * sizeof(float), stream);
  prep_w_kernel<<<144, 256, 0, stream>>>(conv_w, wA);
  conv_kernel<<<kB * kH * 2, 256, 0, stream>>>(x, wA, conv_b, y, sums);
  pack_kernel<<<kB * (kN / 64), 256, 0, stream>>>(y, sums, bn_scale, bn_bias, prelu_a,
                                                  feat, fbfA, fbfQ, fbfB);
  attn_kernel<<<kB * 16 * SPLIT, 256, 0, stream>>>(fbfA, fbfQ, fbfB, Op, lp);
  combine_kernel<<<kB * 64, 256, 0, stream>>>(Op, lp, feat, gamma, out);
}